// Round 1
// baseline (668.207 us; speedup 1.0000x reference)
//
#include <hip/hip_runtime.h>
#include <math.h>

// Problem constants
#define H_   768
#define NH_  12
#define DH_  64
#define NL_  50
#define T_   512
#define NC_  16
#define S_   8192

// ---------------------------------------------------------------------------
// Generic fp32 tiled GEMM: C = alpha * (A @ B^T + bias), row-major.
// A: M x K (lda), B: N x K (ldb), C: M x ldc. Guards on M rows and Nvalid cols.
// blockIdx.z batching via sAz/sBz/sCz element strides.
// ---------------------------------------------------------------------------
template<int BM, int BN, int BK, int TM, int TN>
__global__ __launch_bounds__(256)
void gemm_abt(const float* __restrict__ A, int lda, long sAz,
              const float* __restrict__ B, int ldb, long sBz,
              const float* __restrict__ bias,
              float* __restrict__ C, int ldc, long sCz,
              int M, int Nvalid, int K, float alpha)
{
    constexpr int MG  = TM / 4;       // row register groups
    constexpr int NG  = TN / 4;       // col register groups
    constexpr int RSM = BM / MG;      // row group stride
    constexpr int RSN = BN / NG;      // col group stride

    __shared__ float As[BK][BM];      // transposed: As[k][m]
    __shared__ float Bs[BK][BN];      // transposed: Bs[k][n]

    const int tid = threadIdx.x;
    const int tx  = tid & 15;
    const int ty  = tid >> 4;
    const long m0 = (long)blockIdx.y * BM;
    const long n0 = (long)blockIdx.x * BN;

    A += (long)blockIdx.z * sAz;
    B += (long)blockIdx.z * sBz;
    C += (long)blockIdx.z * sCz;

    float acc[MG][NG][4][4];
    #pragma unroll
    for (int a = 0; a < MG; ++a)
        #pragma unroll
        for (int b = 0; b < NG; ++b)
            #pragma unroll
            for (int i = 0; i < 4; ++i)
                #pragma unroll
                for (int j = 0; j < 4; ++j)
                    acc[a][b][i][j] = 0.f;

    for (int k0 = 0; k0 < K; k0 += BK) {
        // --- stage A tile (BM x BK) transposed into LDS ---
        #pragma unroll
        for (int s = tid; s < BM * BK / 4; s += 256) {
            const int row = s / (BK / 4);
            const int kq  = s % (BK / 4);
            float4 val = make_float4(0.f, 0.f, 0.f, 0.f);
            if (m0 + row < M)
                val = *reinterpret_cast<const float4*>(A + (m0 + row) * lda + k0 + kq * 4);
            As[kq * 4 + 0][row] = val.x;
            As[kq * 4 + 1][row] = val.y;
            As[kq * 4 + 2][row] = val.z;
            As[kq * 4 + 3][row] = val.w;
        }
        // --- stage B tile (BN x BK) transposed into LDS ---
        #pragma unroll
        for (int s = tid; s < BN * BK / 4; s += 256) {
            const int row = s / (BK / 4);
            const int kq  = s % (BK / 4);
            float4 val = make_float4(0.f, 0.f, 0.f, 0.f);
            if (n0 + row < Nvalid)
                val = *reinterpret_cast<const float4*>(B + (n0 + row) * ldb + k0 + kq * 4);
            Bs[kq * 4 + 0][row] = val.x;
            Bs[kq * 4 + 1][row] = val.y;
            Bs[kq * 4 + 2][row] = val.z;
            Bs[kq * 4 + 3][row] = val.w;
        }
        __syncthreads();

        #pragma unroll
        for (int kk = 0; kk < BK; ++kk) {
            float av[MG][4], bv[NG][4];
            #pragma unroll
            for (int g = 0; g < MG; ++g)
                *reinterpret_cast<float4*>(av[g]) =
                    *reinterpret_cast<const float4*>(&As[kk][g * RSM + ty * 4]);
            #pragma unroll
            for (int g = 0; g < NG; ++g)
                *reinterpret_cast<float4*>(bv[g]) =
                    *reinterpret_cast<const float4*>(&Bs[kk][g * RSN + tx * 4]);
            #pragma unroll
            for (int a = 0; a < MG; ++a)
                #pragma unroll
                for (int b = 0; b < NG; ++b)
                    #pragma unroll
                    for (int i = 0; i < 4; ++i)
                        #pragma unroll
                        for (int j = 0; j < 4; ++j)
                            acc[a][b][i][j] += av[a][i] * bv[b][j];
        }
        __syncthreads();
    }

    // --- epilogue: guarded scalar stores ---
    #pragma unroll
    for (int a = 0; a < MG; ++a)
        #pragma unroll
        for (int i = 0; i < 4; ++i) {
            const long row = m0 + a * RSM + ty * 4 + i;
            if (row >= M) continue;
            #pragma unroll
            for (int b = 0; b < NG; ++b)
                #pragma unroll
                for (int j = 0; j < 4; ++j) {
                    const long col = n0 + b * RSN + tx * 4 + j;
                    if (col < Nvalid) {
                        const float bval = bias ? bias[col] : 0.f;
                        C[row * ldc + col] = alpha * (acc[a][b][i][j] + bval);
                    }
                }
        }
}

// ---------------------------------------------------------------------------
// Fused per-chunk attention partials. Block = (l, h, c). 256 threads.
// Computes logits q[l,h,:]·k[s,h,:] for the 512 keys of chunk c, chunk-local
// softmax partials (max m, sum p) and partial context ctx_c[d] = sum w_s v[s,d].
// kv layout: (8192, 1536): k = cols [0,768), v = cols [768,1536).
// q is pre-scaled by 1/sqrt(DH).
// ---------------------------------------------------------------------------
__global__ __launch_bounds__(256)
void attn_partial(const float* __restrict__ kv,
                  const float* __restrict__ q,
                  float* __restrict__ pm,
                  float* __restrict__ pp,
                  float* __restrict__ pctx)
{
    const int l = blockIdx.x;   // 0..49
    const int h = blockIdx.y;   // 0..11
    const int c = blockIdx.z;   // 0..15
    const int tid = threadIdx.x;

    __shared__ float ws[T_];
    __shared__ float red[8];
    __shared__ float paccs[4][DH_];

    // q row into registers (same address across lanes -> broadcast from cache)
    const float* qp = q + (long)l * H_ + h * DH_;
    float4 qr[16];
    #pragma unroll
    for (int i = 0; i < 16; ++i)
        qr[i] = reinterpret_cast<const float4*>(qp)[i];

    // logits for 2 keys per thread
    const float* kbase = kv + (long)c * T_ * (2 * H_) + h * DH_;
    float x[2];
    #pragma unroll
    for (int t = 0; t < 2; ++t) {
        const int sl = tid + t * 256;
        const float4* kp = reinterpret_cast<const float4*>(kbase + (long)sl * (2 * H_));
        float d0 = 0.f, d1 = 0.f, d2 = 0.f, d3 = 0.f;
        #pragma unroll
        for (int i = 0; i < 16; ++i) {
            const float4 kq4 = kp[i];
            d0 += qr[i].x * kq4.x;
            d1 += qr[i].y * kq4.y;
            d2 += qr[i].z * kq4.z;
            d3 += qr[i].w * kq4.w;
        }
        x[t] = (d0 + d1) + (d2 + d3);
    }

    // block max over 512 logits
    float mloc = fmaxf(x[0], x[1]);
    #pragma unroll
    for (int o = 32; o; o >>= 1) mloc = fmaxf(mloc, __shfl_xor(mloc, o));
    const int wid = tid >> 6;
    if ((tid & 63) == 0) red[wid] = mloc;
    __syncthreads();
    const float m = fmaxf(fmaxf(red[0], red[1]), fmaxf(red[2], red[3]));

    // exp weights + block sum
    const float w0 = expf(x[0] - m);
    const float w1 = expf(x[1] - m);
    ws[tid]       = w0;
    ws[tid + 256] = w1;
    float ploc = w0 + w1;
    #pragma unroll
    for (int o = 32; o; o >>= 1) ploc += __shfl_xor(ploc, o);
    if ((tid & 63) == 0) red[4 + wid] = ploc;
    __syncthreads();   // also publishes ws[]
    const float p = red[4] + red[5] + red[6] + red[7];

    // PV: wave wid handles keys [wid*128, wid*128+128); lane owns dim d
    const int lane = tid & 63;
    const float* vbase = kv + (long)c * T_ * (2 * H_) + H_ + h * DH_ + lane;
    float accd = 0.f;
    #pragma unroll 8
    for (int i = 0; i < 128; i += 4) {
        const int sl = wid * 128 + i;
        const float4 wv = *reinterpret_cast<const float4*>(&ws[sl]);
        accd += wv.x * vbase[(long)(sl + 0) * (2 * H_)];
        accd += wv.y * vbase[(long)(sl + 1) * (2 * H_)];
        accd += wv.z * vbase[(long)(sl + 2) * (2 * H_)];
        accd += wv.w * vbase[(long)(sl + 3) * (2 * H_)];
    }
    paccs[wid][lane] = accd;
    __syncthreads();

    if (tid < DH_) {
        const float r = paccs[0][tid] + paccs[1][tid] + paccs[2][tid] + paccs[3][tid];
        const long idx = ((long)c * NH_ + h) * NL_ + l;
        pctx[idx * DH_ + tid] = r;
        if (tid == 0) { pm[idx] = m; pp[idx] = p; }
    }
}

// ---------------------------------------------------------------------------
// Prefix (flash-style) combine over the 16 chunks. Block = (h, l), 64 threads.
// Emits normalized ctx for every prefix c: ctx[(c*NL+l)*H + h*DH + lane].
// ---------------------------------------------------------------------------
__global__ __launch_bounds__(64)
void combine_kernel(const float* __restrict__ pm,
                    const float* __restrict__ pp,
                    const float* __restrict__ pctx,
                    float* __restrict__ ctx)
{
    const int h = blockIdx.x;      // 0..11
    const int l = blockIdx.y;      // 0..49
    const int lane = threadIdx.x;  // 0..63

    float M = -INFINITY, S = 0.f, acc = 0.f;
    for (int c = 0; c < NC_; ++c) {
        const long idx = ((long)c * NH_ + h) * NL_ + l;
        const float mc = pm[idx];
        const float pc = pp[idx];
        const float Mn = fmaxf(M, mc);
        const float ea = expf(M - Mn);
        const float eb = expf(mc - Mn);
        S   = S * ea + pc * eb;
        acc = acc * ea + pctx[idx * DH_ + lane] * eb;
        M   = Mn;
        ctx[((long)c * NL_ + l) * H_ + h * DH_ + lane] = acc / S;
    }
}

// ---------------------------------------------------------------------------
// M2[l,h] = sum_j lw[l,j] * out_w[j,h]   (lw = label_weights viewed (NL, H))
// ---------------------------------------------------------------------------
__global__ __launch_bounds__(256)
void m2_kernel(const float* __restrict__ lw,
               const float* __restrict__ out_w,
               float* __restrict__ M2)
{
    const int hx = threadIdx.x;                  // 0..63
    const int ly = threadIdx.y;                  // 0..3
    const int hcol = blockIdx.x * 64 + hx;       // 0..767
    const int l = blockIdx.y * 4 + ly;
    if (l >= NL_) return;
    float acc = 0.f;
    for (int j = 0; j < H_; ++j)
        acc += lw[(long)l * H_ + j] * out_w[(long)j * H_ + hcol];
    M2[(long)l * H_ + hcol] = acc;
}

// ---------------------------------------------------------------------------
// score[c,l] = sum_i ctx[c,l,i]*M2[l,i] + sum_j lw[l,j]*out_b[j]
// ---------------------------------------------------------------------------
__global__ __launch_bounds__(64)
void score_kernel(const float* __restrict__ ctx,
                  const float* __restrict__ M2,
                  const float* __restrict__ lw,
                  const float* __restrict__ out_b,
                  float* __restrict__ out)
{
    const int l = blockIdx.x;      // 0..49
    const int c = blockIdx.y;      // 0..15
    const int lane = threadIdx.x;  // 0..63
    const float* cp = ctx + ((long)c * NL_ + l) * H_;
    float acc = 0.f;
    #pragma unroll
    for (int i = lane; i < H_; i += 64)
        acc += cp[i] * M2[(long)l * H_ + i] + lw[(long)l * H_ + i] * out_b[i];
    #pragma unroll
    for (int o = 32; o; o >>= 1) acc += __shfl_xor(acc, o);
    if (lane == 0) out[(long)c * NL_ + l] = acc;
}

// ---------------------------------------------------------------------------
extern "C" void kernel_launch(void* const* d_in, const int* in_sizes, int n_in,
                              void* d_out, int out_size, void* d_ws, size_t ws_size,
                              hipStream_t stream) {
    const float* enc = (const float*)d_in[0];   // (8192, 768)
    const float* lq  = (const float*)d_in[1];   // (50, 768)
    const float* lwt = (const float*)d_in[2];   // (768, 50) flat == lw (50, 768)
    const float* ipw = (const float*)d_in[3];   // (2304, 768)
    const float* ipb = (const float*)d_in[4];   // (2304,)
    const float* ow  = (const float*)d_in[5];   // (768, 768)
    const float* ob  = (const float*)d_in[6];   // (768,)
    float* out = (float*)d_out;                 // (16, 50)

    // workspace layout (floats); total ~18.8M floats = ~75.3 MB
    float* ws   = (float*)d_ws;
    float* q    = ws;                            // 50*768
    float* kv   = q    + (long)NL_ * H_;         // 8192*1536
    float* pm   = kv   + (long)S_ * 2 * H_;      // 16*12*50
    float* pp   = pm   + (long)NC_ * NH_ * NL_;
    float* pctx = pp   + (long)NC_ * NH_ * NL_;  // 16*12*50*64
    float* ctx  = pctx + (long)NC_ * NH_ * NL_ * DH_;   // 16*50*768
    float* M2   = ctx  + (long)NC_ * NL_ * H_;   // 50*768

    const float scale = 0.125f;  // 1/sqrt(64)

    // 1. q = scale * (label_queries @ wq^T + bq)     (50 x 768)
    gemm_abt<128, 64, 16, 8, 4><<<dim3(H_ / 64, 1, 1), 256, 0, stream>>>(
        lq, H_, 0, ipw, H_, 0, ipb, q, H_, 0, NL_, H_, H_, scale);

    // 2. kv = enc @ [wk|wv]^T + [bk|bv]              (8192 x 1536)
    gemm_abt<128, 128, 16, 8, 8><<<dim3(2 * H_ / 128, S_ / 128, 1), 256, 0, stream>>>(
        enc, H_, 0, ipw + (long)H_ * H_, H_, 0, ipb + H_, kv, 2 * H_, 0,
        S_, 2 * H_, H_, 1.0f);

    // 3. per-chunk softmax partials + partial PV
    attn_partial<<<dim3(NL_, NH_, NC_), 256, 0, stream>>>(kv, q, pm, pp, pctx);

    // 4. prefix combine -> normalized ctx for every chunk
    combine_kernel<<<dim3(NH_, NL_, 1), 64, 0, stream>>>(pm, pp, pctx, ctx);

    // 5. M2 = lw @ out_w                              (50 x 768)
    m2_kernel<<<dim3(H_ / 64, (NL_ + 3) / 4, 1), dim3(64, 4, 1), 0, stream>>>(lwt, ow, M2);

    // 6. score
    score_kernel<<<dim3(NL_, NC_, 1), 64, 0, stream>>>(ctx, M2, lwt, ob, out);
}

// Round 2
// 331.311 us; speedup vs baseline: 2.0169x; 2.0169x over previous
//
#include <hip/hip_runtime.h>
#include <math.h>

// Problem constants
#define H_   768
#define NH_  12
#define DH_  64
#define NL_  50
#define T_   512
#define NC_  16
#define S_   8192

typedef __attribute__((ext_vector_type(8))) short short8;
typedef __attribute__((ext_vector_type(4))) float f32x4;

#define AS1(p) ((const __attribute__((address_space(1))) void*)(p))
#define AS3(p) ((__attribute__((address_space(3))) void*)(p))

__device__ inline float b2f(unsigned short s) {
    union { float f; unsigned u; } x;
    x.u = ((unsigned)s) << 16;
    return x.f;
}

__device__ inline unsigned short f2b(float f) {
    union { float f; unsigned u; } x;
    x.f = f;
    unsigned r = (x.u + 0x7FFFu + ((x.u >> 16) & 1u)) >> 16;
    return (unsigned short)r;
}

// ---------------------------------------------------------------------------
// fp32 -> bf16 convert (vectorized: float4 in, ushort4 out)
// ---------------------------------------------------------------------------
__global__ __launch_bounds__(256)
void cvt_f32_bf16(const float* __restrict__ in, unsigned short* __restrict__ out, int n4)
{
    const int i = blockIdx.x * 256 + threadIdx.x;
    if (i >= n4) return;
    const float4 v = reinterpret_cast<const float4*>(in)[i];
    ushort4 o;
    o.x = f2b(v.x); o.y = f2b(v.y); o.z = f2b(v.z); o.w = f2b(v.w);
    reinterpret_cast<ushort4*>(out)[i] = o;
}

// ---------------------------------------------------------------------------
// bf16 MFMA GEMM (m97 structure): C = A @ B^T + bias, C stored bf16.
// A: 8192x768 bf16, B: 1536x768 bf16, C: 8192x1536 bf16, bias fp32 (1536).
// 128x128 tile, BK=32, 4 waves (2x2), 4x4 frags of 16x16x32 each.
// ---------------------------------------------------------------------------
__global__ __launch_bounds__(256)
void gemm_kv_mfma(const unsigned short* __restrict__ A,
                  const unsigned short* __restrict__ B,
                  const float* __restrict__ bias,
                  unsigned short* __restrict__ C)
{
    __shared__ unsigned short As[128 * 32];
    __shared__ unsigned short Bs[128 * 32];

    const int tid  = threadIdx.x;
    const int lane = tid & 63;
    const int w    = tid >> 6;
    const int wr   = w >> 1, wc = w & 1;
    const long m0  = (long)blockIdx.y * 128;
    const long n0  = (long)blockIdx.x * 128;

    f32x4 acc[4][4];
    #pragma unroll
    for (int m = 0; m < 4; ++m)
        #pragma unroll
        for (int n = 0; n < 4; ++n)
            #pragma unroll
            for (int j = 0; j < 4; ++j)
                acc[m][n][j] = 0.f;

    const int r0 = tid >> 2;          // chunk row base
    const int k8 = (tid & 3) * 8;     // k offset within tile

    for (int k0 = 0; k0 < 768; k0 += 32) {
        // --- stage A,B tiles via async global->LDS, width 16 B ---
        #pragma unroll
        for (int t = 0; t < 2; ++t) {
            const int row  = t * 64 + r0;
            const int ldso = (t * 256 + tid) * 8;   // elements
            __builtin_amdgcn_global_load_lds(AS1(A + (m0 + row) * 768 + k0 + k8),
                                             AS3(As + ldso), 16, 0, 0);
            __builtin_amdgcn_global_load_lds(AS1(B + (n0 + row) * 768 + k0 + k8),
                                             AS3(Bs + ldso), 16, 0, 0);
        }
        __syncthreads();

        // --- fragments + MFMA ---
        short8 a[4], b[4];
        const int rr = lane & 15, kb = (lane >> 4) * 8;
        #pragma unroll
        for (int m = 0; m < 4; ++m)
            a[m] = *reinterpret_cast<const short8*>(As + (wr * 64 + m * 16 + rr) * 32 + kb);
        #pragma unroll
        for (int n = 0; n < 4; ++n)
            b[n] = *reinterpret_cast<const short8*>(Bs + (wc * 64 + n * 16 + rr) * 32 + kb);
        #pragma unroll
        for (int m = 0; m < 4; ++m)
            #pragma unroll
            for (int n = 0; n < 4; ++n)
                acc[m][n] = __builtin_amdgcn_mfma_f32_16x16x32_bf16(a[m], b[n], acc[m][n], 0, 0, 0);
        __syncthreads();
    }

    // --- epilogue: C/D layout col=lane&15, row=(lane>>4)*4+j  [m89/m91] ---
    const int col16 = lane & 15, row4 = (lane >> 4) * 4;
    #pragma unroll
    for (int m = 0; m < 4; ++m) {
        #pragma unroll
        for (int n = 0; n < 4; ++n) {
            const long col = n0 + wc * 64 + n * 16 + col16;
            const float bv = bias[col];
            #pragma unroll
            for (int j = 0; j < 4; ++j) {
                const long row = m0 + wr * 64 + m * 16 + row4 + j;
                C[row * 1536 + col] = f2b(acc[m][n][j] + bv);
            }
        }
    }
}

// ---------------------------------------------------------------------------
// Generic fp32 tiled GEMM (used only for the small q projection).
// ---------------------------------------------------------------------------
template<int BM, int BN, int BK, int TM, int TN>
__global__ __launch_bounds__(256)
void gemm_abt(const float* __restrict__ A, int lda,
              const float* __restrict__ B, int ldb,
              const float* __restrict__ bias,
              float* __restrict__ C, int ldc,
              int M, int Nvalid, int K, float alpha)
{
    constexpr int MG  = TM / 4;
    constexpr int NG  = TN / 4;
    constexpr int RSM = BM / MG;
    constexpr int RSN = BN / NG;

    __shared__ float As[BK][BM];
    __shared__ float Bs[BK][BN];

    const int tid = threadIdx.x;
    const int tx  = tid & 15;
    const int ty  = tid >> 4;
    const long m0 = (long)blockIdx.y * BM;
    const long n0 = (long)blockIdx.x * BN;

    float acc[MG][NG][4][4];
    #pragma unroll
    for (int a = 0; a < MG; ++a)
        #pragma unroll
        for (int b = 0; b < NG; ++b)
            #pragma unroll
            for (int i = 0; i < 4; ++i)
                #pragma unroll
                for (int j = 0; j < 4; ++j)
                    acc[a][b][i][j] = 0.f;

    for (int k0 = 0; k0 < K; k0 += BK) {
        #pragma unroll
        for (int s = tid; s < BM * BK / 4; s += 256) {
            const int row = s / (BK / 4);
            const int kq  = s % (BK / 4);
            float4 val = make_float4(0.f, 0.f, 0.f, 0.f);
            if (m0 + row < M)
                val = *reinterpret_cast<const float4*>(A + (m0 + row) * lda + k0 + kq * 4);
            As[kq * 4 + 0][row] = val.x;
            As[kq * 4 + 1][row] = val.y;
            As[kq * 4 + 2][row] = val.z;
            As[kq * 4 + 3][row] = val.w;
        }
        #pragma unroll
        for (int s = tid; s < BN * BK / 4; s += 256) {
            const int row = s / (BK / 4);
            const int kq  = s % (BK / 4);
            float4 val = make_float4(0.f, 0.f, 0.f, 0.f);
            if (n0 + row < Nvalid)
                val = *reinterpret_cast<const float4*>(B + (n0 + row) * ldb + k0 + kq * 4);
            Bs[kq * 4 + 0][row] = val.x;
            Bs[kq * 4 + 1][row] = val.y;
            Bs[kq * 4 + 2][row] = val.z;
            Bs[kq * 4 + 3][row] = val.w;
        }
        __syncthreads();

        #pragma unroll
        for (int kk = 0; kk < BK; ++kk) {
            float av[MG][4], bv[NG][4];
            #pragma unroll
            for (int g = 0; g < MG; ++g)
                *reinterpret_cast<float4*>(av[g]) =
                    *reinterpret_cast<const float4*>(&As[kk][g * RSM + ty * 4]);
            #pragma unroll
            for (int g = 0; g < NG; ++g)
                *reinterpret_cast<float4*>(bv[g]) =
                    *reinterpret_cast<const float4*>(&Bs[kk][g * RSN + tx * 4]);
            #pragma unroll
            for (int a = 0; a < MG; ++a)
                #pragma unroll
                for (int b = 0; b < NG; ++b)
                    #pragma unroll
                    for (int i = 0; i < 4; ++i)
                        #pragma unroll
                        for (int j = 0; j < 4; ++j)
                            acc[a][b][i][j] += av[a][i] * bv[b][j];
        }
        __syncthreads();
    }

    #pragma unroll
    for (int a = 0; a < MG; ++a)
        #pragma unroll
        for (int i = 0; i < 4; ++i) {
            const long row = m0 + a * RSM + ty * 4 + i;
            if (row >= M) continue;
            #pragma unroll
            for (int b = 0; b < NG; ++b)
                #pragma unroll
                for (int j = 0; j < 4; ++j) {
                    const long col = n0 + b * RSN + tx * 4 + j;
                    if (col < Nvalid) {
                        const float bval = bias ? bias[col] : 0.f;
                        C[row * ldc + col] = alpha * (acc[a][b][i][j] + bval);
                    }
                }
        }
}

// ---------------------------------------------------------------------------
// Fused per-chunk attention partials, kv in bf16. Block = (l, h, c).
// ---------------------------------------------------------------------------
__global__ __launch_bounds__(256)
void attn_partial(const unsigned short* __restrict__ kv,  // 8192 x 1536 bf16
                  const float* __restrict__ q,            // 50 x 768 fp32, pre-scaled
                  float* __restrict__ pm,
                  float* __restrict__ pp,
                  float* __restrict__ pctx)
{
    const int l = blockIdx.x;   // 0..49
    const int h = blockIdx.y;   // 0..11
    const int c = blockIdx.z;   // 0..15
    const int tid = threadIdx.x;

    __shared__ float ws[T_];
    __shared__ float red[8];
    __shared__ float paccs[4][DH_];

    // q row into registers
    const float* qp = q + (long)l * H_ + h * DH_;
    float qr[64];
    #pragma unroll
    for (int i = 0; i < 16; ++i)
        *reinterpret_cast<float4*>(&qr[i * 4]) = reinterpret_cast<const float4*>(qp)[i];

    // logits for 2 keys per thread
    const unsigned short* kbase = kv + (long)c * T_ * (2 * H_) + h * DH_;
    float x[2];
    #pragma unroll
    for (int t = 0; t < 2; ++t) {
        const int sl = tid + t * 256;
        const short8* kp = reinterpret_cast<const short8*>(kbase + (long)sl * (2 * H_));
        float acc = 0.f;
        #pragma unroll
        for (int i = 0; i < 8; ++i) {
            const short8 kk = kp[i];
            #pragma unroll
            for (int j = 0; j < 8; ++j)
                acc += qr[i * 8 + j] * b2f((unsigned short)kk[j]);
        }
        x[t] = acc;
    }

    // block max over 512 logits
    float mloc = fmaxf(x[0], x[1]);
    #pragma unroll
    for (int o = 32; o; o >>= 1) mloc = fmaxf(mloc, __shfl_xor(mloc, o));
    const int wid = tid >> 6;
    if ((tid & 63) == 0) red[wid] = mloc;
    __syncthreads();
    const float m = fmaxf(fmaxf(red[0], red[1]), fmaxf(red[2], red[3]));

    // exp weights + block sum
    const float w0 = expf(x[0] - m);
    const float w1 = expf(x[1] - m);
    ws[tid]       = w0;
    ws[tid + 256] = w1;
    float ploc = w0 + w1;
    #pragma unroll
    for (int o = 32; o; o >>= 1) ploc += __shfl_xor(ploc, o);
    if ((tid & 63) == 0) red[4 + wid] = ploc;
    __syncthreads();
    const float p = red[4] + red[5] + red[6] + red[7];

    // PV: wave wid handles keys [wid*128, +128); lane owns dim d
    const int lane = tid & 63;
    const unsigned short* vbase = kv + (long)c * T_ * (2 * H_) + H_ + h * DH_ + lane;
    float accd = 0.f;
    #pragma unroll 8
    for (int i = 0; i < 128; i += 4) {
        const int sl = wid * 128 + i;
        const float4 wv = *reinterpret_cast<const float4*>(&ws[sl]);
        accd += wv.x * b2f(vbase[(long)(sl + 0) * (2 * H_)]);
        accd += wv.y * b2f(vbase[(long)(sl + 1) * (2 * H_)]);
        accd += wv.z * b2f(vbase[(long)(sl + 2) * (2 * H_)]);
        accd += wv.w * b2f(vbase[(long)(sl + 3) * (2 * H_)]);
    }
    paccs[wid][lane] = accd;
    __syncthreads();

    if (tid < DH_) {
        const float r = paccs[0][tid] + paccs[1][tid] + paccs[2][tid] + paccs[3][tid];
        const long idx = ((long)c * NH_ + h) * NL_ + l;
        pctx[idx * DH_ + tid] = r;
        if (tid == 0) { pm[idx] = m; pp[idx] = p; }
    }
}

// ---------------------------------------------------------------------------
// Prefix (flash-style) combine over the 16 chunks. Block = (h, l), 64 threads.
// ---------------------------------------------------------------------------
__global__ __launch_bounds__(64)
void combine_kernel(const float* __restrict__ pm,
                    const float* __restrict__ pp,
                    const float* __restrict__ pctx,
                    float* __restrict__ ctx)
{
    const int h = blockIdx.x;
    const int l = blockIdx.y;
    const int lane = threadIdx.x;

    float M = -INFINITY, S = 0.f, acc = 0.f;
    for (int c = 0; c < NC_; ++c) {
        const long idx = ((long)c * NH_ + h) * NL_ + l;
        const float mc = pm[idx];
        const float pc = pp[idx];
        const float Mn = fmaxf(M, mc);
        const float ea = expf(M - Mn);
        const float eb = expf(mc - Mn);
        S   = S * ea + pc * eb;
        acc = acc * ea + pctx[idx * DH_ + lane] * eb;
        M   = Mn;
        ctx[((long)c * NL_ + l) * H_ + h * DH_ + lane] = acc / S;
    }
}

// ---------------------------------------------------------------------------
// M2[l,h] = sum_j lw[l,j] * out_w[j,h]
// ---------------------------------------------------------------------------
__global__ __launch_bounds__(256)
void m2_kernel(const float* __restrict__ lw,
               const float* __restrict__ out_w,
               float* __restrict__ M2)
{
    const int hx = threadIdx.x;
    const int ly = threadIdx.y;
    const int hcol = blockIdx.x * 64 + hx;
    const int l = blockIdx.y * 4 + ly;
    if (l >= NL_) return;
    float acc = 0.f;
    for (int j = 0; j < H_; ++j)
        acc += lw[(long)l * H_ + j] * out_w[(long)j * H_ + hcol];
    M2[(long)l * H_ + hcol] = acc;
}

// ---------------------------------------------------------------------------
// score[c,l] = sum_i ctx[c,l,i]*M2[l,i] + sum_j lw[l,j]*out_b[j]
// ---------------------------------------------------------------------------
__global__ __launch_bounds__(64)
void score_kernel(const float* __restrict__ ctx,
                  const float* __restrict__ M2,
                  const float* __restrict__ lw,
                  const float* __restrict__ out_b,
                  float* __restrict__ out)
{
    const int l = blockIdx.x;
    const int c = blockIdx.y;
    const int lane = threadIdx.x;
    const float* cp = ctx + ((long)c * NL_ + l) * H_;
    float acc = 0.f;
    #pragma unroll
    for (int i = lane; i < H_; i += 64)
        acc += cp[i] * M2[(long)l * H_ + i] + lw[(long)l * H_ + i] * out_b[i];
    #pragma unroll
    for (int o = 32; o; o >>= 1) acc += __shfl_xor(acc, o);
    if (lane == 0) out[(long)c * NL_ + l] = acc;
}

// ---------------------------------------------------------------------------
extern "C" void kernel_launch(void* const* d_in, const int* in_sizes, int n_in,
                              void* d_out, int out_size, void* d_ws, size_t ws_size,
                              hipStream_t stream) {
    const float* enc = (const float*)d_in[0];   // (8192, 768)
    const float* lq  = (const float*)d_in[1];   // (50, 768)
    const float* lwt = (const float*)d_in[2];   // flat == lw (50, 768)
    const float* ipw = (const float*)d_in[3];   // (2304, 768)
    const float* ipb = (const float*)d_in[4];   // (2304,)
    const float* ow  = (const float*)d_in[5];   // (768, 768)
    const float* ob  = (const float*)d_in[6];   // (768,)
    float* out = (float*)d_out;                 // (16, 50)

    // workspace layout: fp32 region first, then bf16 (ushort) region
    float* wsf  = (float*)d_ws;
    float* q    = wsf;                             // 50*768          = 38400
    float* pm   = q    + (long)NL_ * H_;           // 9600
    float* pp   = pm   + (long)NC_ * NH_ * NL_;    // 9600
    float* pctx = pp   + (long)NC_ * NH_ * NL_;    // 614400
    float* ctx  = pctx + (long)NC_ * NH_ * NL_ * DH_;  // 614400
    float* M2   = ctx  + (long)NC_ * NL_ * H_;     // 38400
    unsigned short* enc_b = (unsigned short*)(M2 + (long)NL_ * H_);  // 8192*768
    unsigned short* wkv_b = enc_b + (long)S_ * H_;                   // 1536*768
    unsigned short* kv_b  = wkv_b + (long)2 * H_ * H_;               // 8192*1536

    const float scale = 0.125f;  // 1/sqrt(64)

    // 0. converts to bf16
    cvt_f32_bf16<<<dim3(S_ * H_ / 4 / 256), 256, 0, stream>>>(enc, enc_b, S_ * H_ / 4);
    cvt_f32_bf16<<<dim3(2 * H_ * H_ / 4 / 256), 256, 0, stream>>>(ipw + (long)H_ * H_, wkv_b, 2 * H_ * H_ / 4);

    // 1. q = scale * (label_queries @ wq^T + bq)   (50 x 768, fp32)
    gemm_abt<128, 64, 16, 8, 4><<<dim3(H_ / 64, 1, 1), 256, 0, stream>>>(
        lq, H_, ipw, H_, ipb, q, H_, NL_, H_, H_, scale);

    // 2. kv = enc @ [wk|wv]^T + [bk|bv]  -> bf16   (8192 x 1536)
    gemm_kv_mfma<<<dim3(2 * H_ / 128, S_ / 128, 1), 256, 0, stream>>>(
        enc_b, wkv_b, ipb + H_, kv_b);

    // 3. per-chunk softmax partials + partial PV
    attn_partial<<<dim3(NL_, NH_, NC_), 256, 0, stream>>>(kv_b, q, pm, pp, pctx);

    // 4. prefix combine
    combine_kernel<<<dim3(NH_, NL_, 1), 64, 0, stream>>>(pm, pp, pctx, ctx);

    // 5. M2 = lw @ out_w
    m2_kernel<<<dim3(H_ / 64, (NL_ + 3) / 4, 1), dim3(64, 4, 1), 0, stream>>>(lwt, ow, M2);

    // 6. score
    score_kernel<<<dim3(NL_, NC_, 1), 64, 0, stream>>>(ctx, M2, lwt, ob, out);
}

// Round 3
// 106.883 us; speedup vs baseline: 6.2517x; 3.0997x over previous
//
#include <hip/hip_runtime.h>
#include <math.h>

// Problem constants
#define H_   768
#define NH_  12
#define DH_  64
#define NL_  50
#define T_   512
#define NC_  16
#define S_   8192

typedef __attribute__((ext_vector_type(8))) short short8;
typedef __attribute__((ext_vector_type(4))) float f32x4;
typedef unsigned short u16;

#define AS1(p) ((const __attribute__((address_space(1))) void*)(p))
#define AS3(p) ((__attribute__((address_space(3))) void*)(p))

__device__ inline float b2f(u16 s) {
    union { float f; unsigned u; } x; x.u = ((unsigned)s) << 16; return x.f;
}
__device__ inline u16 f2b(float f) {
    union { float f; unsigned u; } x; x.f = f;
    return (u16)((x.u + 0x7FFFu + ((x.u >> 16) & 1u)) >> 16);
}
// row-swizzle for 512B LDS rows (32x 16B slots): slot ^= f(row)
__device__ inline int swz8(int r) { return (r & 7) ^ (((r >> 3) & 1) << 1); }

// ---------------------------------------------------------------------------
// prep_all: enc->bf16, ipw->bf16, lq->bf16(pad 128 rows), lw->bf16(pad),
// out_w -> bf16 transposed (owt[h][j] = out_w[j][h]).  Flat grid, ranges.
// ---------------------------------------------------------------------------
#define NB_ENC  6144   // 8192*768/4/256
#define NB_IPW  1728   // 2304*768/4/256
#define NB_LQ   96     // 128*768/4/256
#define NB_LW   96
#define NB_OWT  576    // 768*768/4/256

__global__ __launch_bounds__(256)
void prep_all(const float* __restrict__ enc, const float* __restrict__ ipw,
              const float* __restrict__ lq, const float* __restrict__ lwt,
              const float* __restrict__ ow,
              u16* __restrict__ encb, u16* __restrict__ ipwb,
              u16* __restrict__ lqb, u16* __restrict__ lwb, u16* __restrict__ owt)
{
    int b = blockIdx.x;
    const int t = threadIdx.x;
    if (b < NB_ENC) {
        const int i = b * 256 + t;
        const float4 v = reinterpret_cast<const float4*>(enc)[i];
        ushort4 o; o.x = f2b(v.x); o.y = f2b(v.y); o.z = f2b(v.z); o.w = f2b(v.w);
        reinterpret_cast<ushort4*>(encb)[i] = o;
        return;
    }
    b -= NB_ENC;
    if (b < NB_IPW) {
        const int i = b * 256 + t;
        const float4 v = reinterpret_cast<const float4*>(ipw)[i];
        ushort4 o; o.x = f2b(v.x); o.y = f2b(v.y); o.z = f2b(v.z); o.w = f2b(v.w);
        reinterpret_cast<ushort4*>(ipwb)[i] = o;
        return;
    }
    b -= NB_IPW;
    if (b < NB_LQ + NB_LW) {
        const bool isLw = (b >= NB_LQ);
        const int i = (isLw ? b - NB_LQ : b) * 256 + t;
        const int idx = i * 4, row = idx / H_, col = idx % H_;
        ushort4 o = make_ushort4(0, 0, 0, 0);
        if (row < NL_) {
            const float4 v = *reinterpret_cast<const float4*>(
                (isLw ? lwt : lq) + (long)row * H_ + col);
            o.x = f2b(v.x); o.y = f2b(v.y); o.z = f2b(v.z); o.w = f2b(v.w);
        }
        reinterpret_cast<ushort4*>(isLw ? lwb : lqb)[i] = o;
        return;
    }
    b -= NB_LQ + NB_LW;
    {
        const int i = b * 256 + t;
        const int idx = i * 4, h = idx / H_, j0 = idx % H_;
        ushort4 o;
        o.x = f2b(ow[(long)(j0 + 0) * H_ + h]);
        o.y = f2b(ow[(long)(j0 + 1) * H_ + h]);
        o.z = f2b(ow[(long)(j0 + 2) * H_ + h]);
        o.w = f2b(ow[(long)(j0 + 3) * H_ + h]);
        reinterpret_cast<ushort4*>(owt)[i] = o;
    }
}

// ---------------------------------------------------------------------------
// gemm_all: one launch, three tasks (m97 structure, 128x128 tile, BK=32).
//  by<64 : KV  : encb(8192x768) @ (ipwb+768*768)(1536x768)^T + ipb[768+] ->
//                 n<768: k_b[row][n] bf16 ; n>=768: vt_b[n-768][row] bf16
//  by==64: Q   : lqb(128x768) @ ipwb(768x768)^T + ipb -> q_b bf16, *0.125
//  by==65: M2  : lwb(128x768) @ owt(768x768)^T -> M2f f32
// ---------------------------------------------------------------------------
__global__ __launch_bounds__(256)
void gemm_all(const u16* __restrict__ encb, const u16* __restrict__ ipwb,
              const u16* __restrict__ lqb,  const u16* __restrict__ lwb,
              const u16* __restrict__ owt,  const float* __restrict__ ipb,
              u16* __restrict__ k_b, u16* __restrict__ vt_b,
              u16* __restrict__ q_b, float* __restrict__ M2f)
{
    const int bx = blockIdx.x, by = blockIdx.y;
    const u16 *A, *B;
    const float* bias = nullptr;
    int mode;
    long m0 = 0;
    if (by < 64)      { mode = 0; A = encb; B = ipwb + (long)H_ * H_; bias = ipb + H_; m0 = (long)by * 128; }
    else if (by == 64){ if (bx >= 6) return; mode = 1; A = lqb; B = ipwb; bias = ipb; }
    else              { if (bx >= 6) return; mode = 2; A = lwb; B = owt; }
    const long n0 = (long)bx * 128;

    __shared__ u16 As[128 * 32];
    __shared__ u16 Bs[128 * 32];

    const int tid  = threadIdx.x;
    const int lane = tid & 63;
    const int w    = tid >> 6;
    const int wr   = w >> 1, wc = w & 1;

    f32x4 acc[4][4];
    #pragma unroll
    for (int m = 0; m < 4; ++m)
        #pragma unroll
        for (int n = 0; n < 4; ++n)
            #pragma unroll
            for (int j = 0; j < 4; ++j) acc[m][n][j] = 0.f;

    const int r0 = tid >> 2;
    const int k8 = (tid & 3) * 8;

    for (int k0 = 0; k0 < H_; k0 += 32) {
        #pragma unroll
        for (int t = 0; t < 2; ++t) {
            const int row  = t * 64 + r0;
            const int ldso = (t * 256 + tid) * 8;
            __builtin_amdgcn_global_load_lds(AS1(A + (m0 + row) * H_ + k0 + k8),
                                             AS3(As + ldso), 16, 0, 0);
            __builtin_amdgcn_global_load_lds(AS1(B + (n0 + row) * H_ + k0 + k8),
                                             AS3(Bs + ldso), 16, 0, 0);
        }
        __syncthreads();

        short8 a[4], bfr[4];
        const int rr = lane & 15, kb = (lane >> 4) * 8;
        #pragma unroll
        for (int m = 0; m < 4; ++m)
            a[m] = *reinterpret_cast<const short8*>(As + (wr * 64 + m * 16 + rr) * 32 + kb);
        #pragma unroll
        for (int n = 0; n < 4; ++n)
            bfr[n] = *reinterpret_cast<const short8*>(Bs + (wc * 64 + n * 16 + rr) * 32 + kb);
        #pragma unroll
        for (int m = 0; m < 4; ++m)
            #pragma unroll
            for (int n = 0; n < 4; ++n)
                acc[m][n] = __builtin_amdgcn_mfma_f32_16x16x32_bf16(a[m], bfr[n], acc[m][n], 0, 0, 0);
        __syncthreads();
    }

    const int col16 = lane & 15, row4 = (lane >> 4) * 4;
    #pragma unroll
    for (int m = 0; m < 4; ++m) {
        #pragma unroll
        for (int n = 0; n < 4; ++n) {
            const long col = n0 + wc * 64 + n * 16 + col16;
            const float bv = bias ? bias[col] : 0.f;
            #pragma unroll
            for (int j = 0; j < 4; ++j) {
                const long row = m0 + wr * 64 + m * 16 + row4 + j;
                const float v = acc[m][n][j] + bv;
                if (mode == 0) {
                    if (col < H_) k_b[row * H_ + col] = f2b(v);
                    else          vt_b[(col - H_) * (long)S_ + row] = f2b(v);
                } else if (mode == 1) {
                    q_b[row * H_ + col] = f2b(v * 0.125f);
                } else {
                    M2f[row * H_ + col] = v;
                }
            }
        }
    }
}

// ---------------------------------------------------------------------------
// attn: block = (h, c). 256 threads (4 waves). Computes chunk-local softmax
// partials for all 50 labels via MFMA.
//  - K staged swizzled in 2 halves of 256 keys (bufA/bufB, 32KB each)
//  - QK^T: wave w owns keys [w*64, w*64+64) of each half, all 64 label rows
//  - block softmax (max, sum) via in-lane + shfl + LDS reduce
//  - P (bf16, swizzled) -> bufA; V^T staged swizzled -> bufB; PV via MFMA,
//    wave w owns label tile w.
// ---------------------------------------------------------------------------
__global__ __launch_bounds__(256, 1)
void attn(const u16* __restrict__ q_b, const u16* __restrict__ k_b,
          const u16* __restrict__ vt_b,
          float* __restrict__ pm, float* __restrict__ pp, float* __restrict__ pctx)
{
    const int h = blockIdx.x;   // 0..11
    const int c = blockIdx.y;   // 0..15
    const int tid  = threadIdx.x;
    const int lane = tid & 63;
    const int w    = tid >> 6;
    const int g    = lane >> 4;
    const int l15  = lane & 15;

    __shared__ u16 bufA[16384];   // 32KB: K half0 -> (red overlay) -> P
    __shared__ u16 bufB[16384];   // 32KB: K half1 -> Vt half0 -> Vt half1
    float* red = (float*)bufA;    // [0..256) red_m, [256..512) red_s, [512..576) mg

    // --- Q fragments (global, tiny; issue first) ---
    short8 aq[4][2];
    #pragma unroll
    for (int lt = 0; lt < 4; ++lt)
        #pragma unroll
        for (int ks = 0; ks < 2; ++ks)
            aq[lt][ks] = *reinterpret_cast<const short8*>(
                q_b + (long)(lt * 16 + l15) * H_ + h * DH_ + ks * 32 + g * 8);

    // --- stage K half0 -> bufA (pre-swizzled source) ---
    const long kchunk = (long)c * T_ * H_ + h * DH_;
    #pragma unroll
    for (int p = 0; p < 8; ++p) {
        const int sl   = p * 32 + (tid >> 3);            // local key 0..255
        const int dq   = (tid & 7) ^ (sl & 7);
        const int ldso = (p * 4096 + tid * 16) / 2;      // elements
        __builtin_amdgcn_global_load_lds(AS1(k_b + kchunk + (long)sl * H_ + dq * 8),
                                         AS3(bufA + ldso), 16, 0, 0);
    }
    __syncthreads();
    // --- stage K half1 -> bufB ---
    #pragma unroll
    for (int p = 0; p < 8; ++p) {
        const int sl   = p * 32 + (tid >> 3);
        const int dq   = (tid & 7) ^ (sl & 7);
        const int ldso = (p * 4096 + tid * 16) / 2;
        __builtin_amdgcn_global_load_lds(AS1(k_b + kchunk + (long)(256 + sl) * H_ + dq * 8),
                                         AS3(bufB + ldso), 16, 0, 0);
    }

    // --- QK^T ---  acc[lt][half*4+st] : lane holds col s = (lane&15), rows l
    f32x4 acc[4][8];
    #pragma unroll
    for (int lt = 0; lt < 4; ++lt)
        #pragma unroll
        for (int st = 0; st < 8; ++st)
            #pragma unroll
            for (int j = 0; j < 4; ++j) acc[lt][st][j] = 0.f;

    #pragma unroll
    for (int half = 0; half < 2; ++half) {
        const u16* buf = half ? bufB : bufA;
        if (half) __syncthreads();   // half1 staged
        #pragma unroll
        for (int ks = 0; ks < 2; ++ks) {
            short8 bk[4];
            #pragma unroll
            for (int st = 0; st < 4; ++st) {
                const int sl = w * 64 + st * 16 + l15;
                const int byte = sl * 128 + (((ks * 4 + g) ^ (sl & 7)) << 4);
                bk[st] = *reinterpret_cast<const short8*>((const char*)buf + byte);
            }
            #pragma unroll
            for (int lt = 0; lt < 4; ++lt)
                #pragma unroll
                for (int st = 0; st < 4; ++st)
                    acc[lt][half * 4 + st] = __builtin_amdgcn_mfma_f32_16x16x32_bf16(
                        aq[lt][ks], bk[st], acc[lt][half * 4 + st], 0, 0, 0);
        }
    }

    // --- block max: in-lane over 8 s-tiles, shfl over 16-lane group ---
    float mx[4][4];
    #pragma unroll
    for (int lt = 0; lt < 4; ++lt)
        #pragma unroll
        for (int j = 0; j < 4; ++j) {
            float m = acc[lt][0][j];
            #pragma unroll
            for (int st = 1; st < 8; ++st) m = fmaxf(m, acc[lt][st][j]);
            #pragma unroll
            for (int o = 1; o < 16; o <<= 1) m = fmaxf(m, __shfl_xor(m, o));
            mx[lt][j] = m;
        }
    if (l15 == 0) {
        #pragma unroll
        for (int lt = 0; lt < 4; ++lt)
            #pragma unroll
            for (int j = 0; j < 4; ++j)
                red[w * 64 + lt * 16 + g * 4 + j] = mx[lt][j];
    }
    __syncthreads();   // [B1] red_m ready; bufB K-reads done by all waves

    // --- issue Vt half0 stage -> bufB (overlaps softmax) ---
    const long vbase = (long)h * DH_ * S_ + c * T_;
    #pragma unroll
    for (int p = 0; p < 8; ++p) {
        const int d    = p * 8 + (tid >> 5);             // 0..63
        const int sc   = (tid & 31) ^ swz8(d);
        const int ldso = (p * 4096 + tid * 16) / 2;
        __builtin_amdgcn_global_load_lds(AS1(vt_b + vbase + (long)d * S_ + sc * 8),
                                         AS3(bufB + ldso), 16, 0, 0);
    }
    if (tid < 64)
        red[512 + tid] = fmaxf(fmaxf(red[tid], red[64 + tid]),
                               fmaxf(red[128 + tid], red[192 + tid]));
    __syncthreads();   // [B2] mg ready

    // --- exp + sums ---
    float mg[4][4];
    #pragma unroll
    for (int lt = 0; lt < 4; ++lt)
        #pragma unroll
        for (int j = 0; j < 4; ++j) mg[lt][j] = red[512 + lt * 16 + g * 4 + j];
    #pragma unroll
    for (int lt = 0; lt < 4; ++lt)
        #pragma unroll
        for (int st = 0; st < 8; ++st)
            #pragma unroll
            for (int j = 0; j < 4; ++j)
                acc[lt][st][j] = __expf(acc[lt][st][j] - mg[lt][j]);
    float sx[4][4];
    #pragma unroll
    for (int lt = 0; lt < 4; ++lt)
        #pragma unroll
        for (int j = 0; j < 4; ++j) {
            float s = 0.f;
            #pragma unroll
            for (int st = 0; st < 8; ++st) s += acc[lt][st][j];
            #pragma unroll
            for (int o = 1; o < 16; o <<= 1) s += __shfl_xor(s, o);
            sx[lt][j] = s;
        }
    if (l15 == 0) {
        #pragma unroll
        for (int lt = 0; lt < 4; ++lt)
            #pragma unroll
            for (int j = 0; j < 4; ++j)
                red[256 + w * 64 + lt * 16 + g * 4 + j] = sx[lt][j];
    }
    __syncthreads();   // [B3] red_s ready

    if (tid < NL_) {
        const long idx = ((long)c * NH_ + h) * NL_ + tid;
        pm[idx] = red[512 + tid];
        pp[idx] = red[256 + tid] + red[320 + tid] + red[384 + tid] + red[448 + tid];
    }
    __syncthreads();   // [B4] red reads done; Vt half0 ready (vmcnt drained)

    // --- write P half0 (bf16, swizzled) -> bufA ---
    #pragma unroll
    for (int lt = 0; lt < 4; ++lt)
        #pragma unroll
        for (int st = 0; st < 4; ++st)
            #pragma unroll
            for (int j = 0; j < 4; ++j) {
                const int l  = lt * 16 + g * 4 + j;
                const int sl = w * 64 + st * 16 + l15;
                const int byte = l * 512 + ((sl * 2) ^ (swz8(l) << 4));
                *(u16*)((char*)bufA + byte) = f2b(acc[lt][st][j]);
            }
    __syncthreads();   // [B5] P half0 + Vt half0 ready

    // --- PV half0 : wave w owns label tile w ---
    f32x4 acc2[4];
    #pragma unroll
    for (int dt = 0; dt < 4; ++dt)
        #pragma unroll
        for (int j = 0; j < 4; ++j) acc2[dt][j] = 0.f;

    const int lrow = w * 16 + l15;
    const int lswz = swz8(lrow) << 4;
    #pragma unroll
    for (int ks = 0; ks < 8; ++ks) {
        const int ch = ks * 4 + g;
        const short8 pa = *reinterpret_cast<const short8*>(
            (const char*)bufA + lrow * 512 + ((ch << 4) ^ lswz));
        #pragma unroll
        for (int dt = 0; dt < 4; ++dt) {
            const int d = dt * 16 + l15;
            const short8 vb = *reinterpret_cast<const short8*>(
                (const char*)bufB + d * 512 + ((ch ^ swz8(d)) << 4));
            acc2[dt] = __builtin_amdgcn_mfma_f32_16x16x32_bf16(pa, vb, acc2[dt], 0, 0, 0);
        }
    }
    __syncthreads();   // [B6] PV half0 reads done everywhere

    // --- stage Vt half1 -> bufB ; write P half1 -> bufA ---
    #pragma unroll
    for (int p = 0; p < 8; ++p) {
        const int d    = p * 8 + (tid >> 5);
        const int sc   = (tid & 31) ^ swz8(d);
        const int ldso = (p * 4096 + tid * 16) / 2;
        __builtin_amdgcn_global_load_lds(AS1(vt_b + vbase + (long)d * S_ + 256 + sc * 8),
                                         AS3(bufB + ldso), 16, 0, 0);
    }
    #pragma unroll
    for (int lt = 0; lt < 4; ++lt)
        #pragma unroll
        for (int st = 0; st < 4; ++st)
            #pragma unroll
            for (int j = 0; j < 4; ++j) {
                const int l  = lt * 16 + g * 4 + j;
                const int sl = w * 64 + st * 16 + l15;
                const int byte = l * 512 + ((sl * 2) ^ (swz8(l) << 4));
                *(u16*)((char*)bufA + byte) = f2b(acc[lt][4 + st][j]);
            }
    __syncthreads();   // [B7] P half1 + Vt half1 ready

    // --- PV half1 ---
    #pragma unroll
    for (int ks = 0; ks < 8; ++ks) {
        const int ch = ks * 4 + g;
        const short8 pa = *reinterpret_cast<const short8*>(
            (const char*)bufA + lrow * 512 + ((ch << 4) ^ lswz));
        #pragma unroll
        for (int dt = 0; dt < 4; ++dt) {
            const int d = dt * 16 + l15;
            const short8 vb = *reinterpret_cast<const short8*>(
                (const char*)bufB + d * 512 + ((ch ^ swz8(d)) << 4));
            acc2[dt] = __builtin_amdgcn_mfma_f32_16x16x32_bf16(pa, vb, acc2[dt], 0, 0, 0);
        }
    }

    // --- store pctx ---
    #pragma unroll
    for (int dt = 0; dt < 4; ++dt)
        #pragma unroll
        for (int j = 0; j < 4; ++j) {
            const int l = w * 16 + g * 4 + j;
            if (l < NL_) {
                const long idx = ((long)c * NH_ + h) * NL_ + l;
                pctx[idx * DH_ + dt * 16 + l15] = acc2[dt][j];
            }
        }
}

// ---------------------------------------------------------------------------
// combine_score: block = label l. Prefix-combine partials over chunks and
// dot with M2 row; emits score[c,l] for all c.
// ---------------------------------------------------------------------------
__global__ __launch_bounds__(256)
void combine_score(const float* __restrict__ pm, const float* __restrict__ pp,
                   const float* __restrict__ pctx, const float* __restrict__ M2f,
                   const float* __restrict__ lw, const float* __restrict__ ob,
                   float* __restrict__ out)
{
    const int l = blockIdx.x;
    const int tid = threadIdx.x;
    const int w = tid >> 6, lane = tid & 63;
    __shared__ float wred[4], bred[4];

    // bias term (constant over c)
    float bp = 0.f;
    #pragma unroll
    for (int r = 0; r < 3; ++r) {
        const int i = tid + 256 * r;
        bp += lw[(long)l * H_ + i] * ob[i];
    }
    #pragma unroll
    for (int o = 1; o < 64; o <<= 1) bp += __shfl_xor(bp, o);
    if (lane == 0) bred[w] = bp;

    float M[3], Ssum[3], A[3];
    #pragma unroll
    for (int r = 0; r < 3; ++r) { M[r] = -INFINITY; Ssum[r] = 0.f; A[r] = 0.f; }

    for (int c = 0; c < NC_; ++c) {
        float t = 0.f;
        #pragma unroll
        for (int r = 0; r < 3; ++r) {
            const int i = tid + 256 * r;
            const int hh = i >> 6, d = i & 63;
            const long idx = ((long)c * NH_ + hh) * NL_ + l;
            const float mc = pm[idx], pc = pp[idx];
            const float Mn = fmaxf(M[r], mc);
            const float ea = __expf(M[r] - Mn), eb = __expf(mc - Mn);
            Ssum[r] = Ssum[r] * ea + pc * eb;
            A[r]    = A[r] * ea + pctx[idx * DH_ + d] * eb;
            M[r] = Mn;
            t += (A[r] / Ssum[r]) * M2f[(long)l * H_ + i];
        }
        #pragma unroll
        for (int o = 1; o < 64; o <<= 1) t += __shfl_xor(t, o);
        if (lane == 0) wred[w] = t;
        __syncthreads();
        if (tid == 0)
            out[(long)c * NL_ + l] = wred[0] + wred[1] + wred[2] + wred[3]
                                   + bred[0] + bred[1] + bred[2] + bred[3];
        __syncthreads();
    }
}

// ---------------------------------------------------------------------------
extern "C" void kernel_launch(void* const* d_in, const int* in_sizes, int n_in,
                              void* d_out, int out_size, void* d_ws, size_t ws_size,
                              hipStream_t stream) {
    const float* enc = (const float*)d_in[0];
    const float* lq  = (const float*)d_in[1];
    const float* lwt = (const float*)d_in[2];
    const float* ipw = (const float*)d_in[3];
    const float* ipb = (const float*)d_in[4];
    const float* ow  = (const float*)d_in[5];
    const float* ob  = (const float*)d_in[6];
    float* out = (float*)d_out;

    // workspace: f32 region then bf16 region (all 16B-aligned)
    float* wsf  = (float*)d_ws;
    float* pctx = wsf;                                   // 16*12*50*64 = 614400
    float* M2f  = pctx + (long)NC_ * NH_ * NL_ * DH_;    // 128*768     =  98304
    float* pm   = M2f + (long)128 * H_;                  // 9600
    float* pp   = pm + (long)NC_ * NH_ * NL_;            // 9600
    u16* encb = (u16*)(pp + (long)NC_ * NH_ * NL_);      // 8192*768
    u16* ipwb = encb + (long)S_ * H_;                    // 2304*768
    u16* lqb  = ipwb + (long)3 * H_ * H_;                // 128*768
    u16* lwb  = lqb + (long)128 * H_;                    // 128*768
    u16* owt  = lwb + (long)128 * H_;                    // 768*768
    u16* q_b  = owt + (long)H_ * H_;                     // 128*768
    u16* k_b  = q_b + (long)128 * H_;                    // 8192*768
    u16* vt_b = k_b + (long)S_ * H_;                     // 768*8192

    prep_all<<<dim3(NB_ENC + NB_IPW + NB_LQ + NB_LW + NB_OWT), 256, 0, stream>>>(
        enc, ipw, lq, lwt, ow, encb, ipwb, lqb, lwb, owt);

    gemm_all<<<dim3(12, 66), 256, 0, stream>>>(
        encb, ipwb, lqb, lwb, owt, ipb, k_b, vt_b, q_b, M2f);

    attn<<<dim3(NH_, NC_), 256, 0, stream>>>(q_b, k_b, vt_b, pm, pp, pctx);

    combine_score<<<dim3(NL_), 256, 0, stream>>>(pm, pp, pctx, M2f, lwt, ob, out);
}